// Round 2
// baseline (321.630 us; speedup 1.0000x reference)
//
#include <hip/hip_runtime.h>
#include <hip/hip_bf16.h>
#include <math.h>

#define N_NODES 50000
#define N_EDGES 800000
#define N_FEAT 128
#define HIDDEN 16
#define N_CLASSES 16

// ---------------------------------------------------------------------------
// K1: per-node transform for layer 1.
// h0 = x@w1[0], h1 = x@w1[1], p1 = x@root1 + b1.
// AB[N][32]: cols 0..15 = h0, 16..31 = h1 (one 128B row per node).
// ---------------------------------------------------------------------------
__global__ __launch_bounds__(256) void k_node1(
    const float* __restrict__ x, const float* __restrict__ w1,
    const float* __restrict__ root1, const float* __restrict__ b1,
    float* __restrict__ AB, float* __restrict__ C)
{
    __shared__ float W[48 * 132];
    for (int t = threadIdx.x; t < 48 * 128; t += 256) {
        int o = t >> 7;        // 0..47
        int i = t & 127;       // 0..127
        float v;
        if (o < 16)       v = w1[i * 16 + o];
        else if (o < 32)  v = w1[2048 + i * 16 + (o - 16)];
        else              v = root1[i * 16 + (o - 32)];
        W[o * 132 + i] = v;
    }
    __syncthreads();

    int nl = threadIdx.x >> 4;
    int o  = threadIdx.x & 15;
    int n  = blockIdx.x * 16 + nl;      // 3125*16 = 50000 exact

    const float4* xr = (const float4*)(x + (size_t)n * N_FEAT);
    float a0 = 0.f, a1 = 0.f, ar = 0.f;
#pragma unroll
    for (int i4 = 0; i4 < 32; ++i4) {
        float4 xv = xr[i4];
        float4 wa = *(const float4*)&W[o * 132 + 4 * i4];
        float4 wb = *(const float4*)&W[(o + 16) * 132 + 4 * i4];
        float4 wr = *(const float4*)&W[(o + 32) * 132 + 4 * i4];
        a0 += xv.x * wa.x + xv.y * wa.y + xv.z * wa.z + xv.w * wa.w;
        a1 += xv.x * wb.x + xv.y * wb.y + xv.z * wb.z + xv.w * wb.w;
        ar += xv.x * wr.x + xv.y * wr.y + xv.z * wr.z + xv.w * wr.w;
    }
    AB[(size_t)n * 32 + o]      = a0;
    AB[(size_t)n * 32 + 16 + o] = a1;
    C[(size_t)n * 16 + o]       = ar + b1[o];
}

// ---------------------------------------------------------------------------
// CSR build: histogram of dst, exclusive scan, stable-ish reorder.
// ---------------------------------------------------------------------------
__global__ __launch_bounds__(256) void k_hist(
    const int* __restrict__ dst, int* __restrict__ cnt)
{
    int e = blockIdx.x * 256 + threadIdx.x;   // 3125*256 = 800000 exact
    atomicAdd(&cnt[dst[e]], 1);
}

#define SCAN_CHUNK 49   // ceil(50000/1024)
__global__ __launch_bounds__(1024) void k_scan(
    const int* __restrict__ cnt, int* __restrict__ rowptr,
    int* __restrict__ cursor)
{
    __shared__ int part[1024];
    int t = threadIdx.x;
    int beg = t * SCAN_CHUNK;
    int end = min(beg + SCAN_CHUNK, N_NODES);
    int sum = 0;
    for (int i = beg; i < end; ++i) sum += cnt[i];
    part[t] = sum;
    __syncthreads();
    for (int off = 1; off < 1024; off <<= 1) {
        int v = (t >= off) ? part[t - off] : 0;
        __syncthreads();
        part[t] += v;
        __syncthreads();
    }
    int excl = (t == 0) ? 0 : part[t - 1];
    for (int i = beg; i < end; ++i) {
        rowptr[i] = excl;
        cursor[i] = excl;
        excl += cnt[i];
    }
    if (t == 0) rowptr[N_NODES] = N_EDGES;
}

__global__ __launch_bounds__(256) void k_reorder(
    const int* __restrict__ src, const int* __restrict__ dst,
    const float* __restrict__ u, int* __restrict__ cursor,
    int* __restrict__ es, float* __restrict__ eu)
{
    int e = blockIdx.x * 256 + threadIdx.x;   // exact
    int d = dst[e];
    int pos = atomicAdd(&cursor[d], 1);
    es[pos] = src[e];
    eu[pos] = u[e];
}

// ---------------------------------------------------------------------------
// Gather-mean: one wave per dst node. Lane = (g=lane>>4 edge slot, o=lane&15
// feature). 4 edges per iteration; shuffle-reduce over g; coalesced 64B write
// of agg/deg (mean fused; deg = row length).
// ---------------------------------------------------------------------------
__global__ __launch_bounds__(256) void k_gather(
    const int* __restrict__ rowptr, const int* __restrict__ es,
    const float* __restrict__ eu, const float* __restrict__ AB,
    float* __restrict__ AGG)
{
    int wave = (blockIdx.x * 256 + threadIdx.x) >> 6;  // = node, 12500*4 = 50000
    int lane = threadIdx.x & 63;
    int o = lane & 15;
    int g = lane >> 4;
    int n = wave;
    int beg = rowptr[n], end = rowptr[n + 1];
    float acc = 0.f;
    for (int e = beg + g; e < end; e += 4) {
        int s = es[e];
        float uv = eu[e];
        acc += (1.f - uv) * AB[(size_t)s * 32 + o]
             +        uv  * AB[(size_t)s * 32 + 16 + o];
    }
    acc += __shfl_xor(acc, 16);
    acc += __shfl_xor(acc, 32);
    float dv = fmaxf((float)(end - beg), 1.f);
    if (lane < 16) AGG[(size_t)n * 16 + o] = acc / dv;
}

// ---------------------------------------------------------------------------
// K3: finish layer 1 (agg already meaned) + ELU + layer-2 node transform.
// ---------------------------------------------------------------------------
__global__ __launch_bounds__(256) void k_node2(
    const float* __restrict__ agg, float* __restrict__ C,
    const float* __restrict__ w2, const float* __restrict__ root2,
    const float* __restrict__ b2, float* __restrict__ AB)
{
    __shared__ float W2[16 * 48];
    __shared__ float hl[16][17];
    for (int t = threadIdx.x; t < 16 * 48; t += 256) {
        int j = t / 48, o = t % 48;
        float v;
        if (o < 16)       v = w2[j * 16 + o];
        else if (o < 32)  v = w2[256 + j * 16 + (o - 16)];
        else              v = root2[j * 16 + (o - 32)];
        W2[t] = v;
    }
    int nl = threadIdx.x >> 4;
    int o  = threadIdx.x & 15;
    int n  = blockIdx.x * 16 + nl;

    float pre = agg[(size_t)n * 16 + o] + C[(size_t)n * 16 + o];
    float h   = pre > 0.f ? pre : expm1f(pre);
    __syncthreads();
    hl[nl][o] = h;
    __syncthreads();

    float a = 0.f, b = 0.f, p = 0.f;
#pragma unroll
    for (int j = 0; j < 16; ++j) {
        float hv = hl[nl][j];
        a += hv * W2[j * 48 + o];
        b += hv * W2[j * 48 + 16 + o];
        p += hv * W2[j * 48 + 32 + o];
    }
    AB[(size_t)n * 32 + o]      = a;
    AB[(size_t)n * 32 + 16 + o] = b;
    C[(size_t)n * 16 + o]       = p + b2[o];
}

// ---------------------------------------------------------------------------
// K5: log_softmax over 16 classes (agg already meaned).
// ---------------------------------------------------------------------------
__global__ __launch_bounds__(256) void k_final(
    const float* __restrict__ agg, const float* __restrict__ C,
    float* __restrict__ out)
{
    int t = blockIdx.x * 256 + threadIdx.x;
    int n = t >> 4;
    int o = t & 15;
    float v = agg[(size_t)n * 16 + o] + C[(size_t)n * 16 + o];
    float m = v;
#pragma unroll
    for (int s = 1; s < 16; s <<= 1) m = fmaxf(m, __shfl_xor(m, s, 16));
    float ex = __expf(v - m);
    float ssum = ex;
#pragma unroll
    for (int s = 1; s < 16; s <<= 1) ssum += __shfl_xor(ssum, s, 16);
    out[(size_t)n * 16 + o] = v - m - __logf(ssum);
}

extern "C" void kernel_launch(void* const* d_in, const int* in_sizes, int n_in,
                              void* d_out, int out_size, void* d_ws, size_t ws_size,
                              hipStream_t stream) {
    const float* x     = (const float*)d_in[0];
    const int*   ei    = (const int*)d_in[1];
    const float* ea    = (const float*)d_in[2];
    const float* w1    = (const float*)d_in[3];
    const float* root1 = (const float*)d_in[4];
    const float* b1    = (const float*)d_in[5];
    const float* w2    = (const float*)d_in[6];
    const float* root2 = (const float*)d_in[7];
    const float* b2    = (const float*)d_in[8];
    float* out = (float*)d_out;

    char* ws = (char*)d_ws;
    float* AB     = (float*)ws;                                   // N*32
    float* C      = AB + (size_t)N_NODES * 32;                    // N*16
    float* AGG    = C + (size_t)N_NODES * 16;                     // N*16
    float* EU     = AGG + (size_t)N_NODES * 16;                   // E
    int*   ES     = (int*)(EU + N_EDGES);                         // E
    int*   CNT    = ES + N_EDGES;                                 // N
    int*   ROWPTR = CNT + N_NODES;                                // N+1
    int*   CURSOR = ROWPTR + (N_NODES + 1);                       // N

    const int* srcp = ei;
    const int* dstp = ei + N_EDGES;

    hipMemsetAsync(CNT, 0, (size_t)N_NODES * sizeof(int), stream);

    k_node1<<<N_NODES / 16, 256, 0, stream>>>(x, w1, root1, b1, AB, C);
    k_hist<<<N_EDGES / 256, 256, 0, stream>>>(dstp, CNT);
    k_scan<<<1, 1024, 0, stream>>>(CNT, ROWPTR, CURSOR);
    k_reorder<<<N_EDGES / 256, 256, 0, stream>>>(srcp, dstp, ea, CURSOR, ES, EU);

    k_gather<<<N_NODES / 4, 256, 0, stream>>>(ROWPTR, ES, EU, AB, AGG);
    k_node2<<<N_NODES / 16, 256, 0, stream>>>(AGG, C, w2, root2, b2, AB);
    k_gather<<<N_NODES / 4, 256, 0, stream>>>(ROWPTR, ES, EU, AB, AGG);
    k_final<<<N_NODES / 16, 256, 0, stream>>>(AGG, C, out);
}

// Round 3
// 224.461 us; speedup vs baseline: 1.4329x; 1.4329x over previous
//
#include <hip/hip_runtime.h>
#include <hip/hip_bf16.h>
#include <math.h>

#define N_NODES 50000
#define N_EDGES 800000
#define N_FEAT 128
#define HIDDEN 16
#define N_CLASSES 16

#define SCAN_NB 196   // ceil(50000/256)

// ---------------------------------------------------------------------------
// K1: per-node transform for layer 1.
// h0 = x@w1[0], h1 = x@w1[1], p1 = x@root1 + b1.
// AB[N][32]: cols 0..15 = h0, 16..31 = h1 (one 128B row per node).
// ---------------------------------------------------------------------------
__global__ __launch_bounds__(256) void k_node1(
    const float* __restrict__ x, const float* __restrict__ w1,
    const float* __restrict__ root1, const float* __restrict__ b1,
    float* __restrict__ AB, float* __restrict__ C)
{
    __shared__ float W[48 * 132];
    for (int t = threadIdx.x; t < 48 * 128; t += 256) {
        int o = t >> 7;
        int i = t & 127;
        float v;
        if (o < 16)       v = w1[i * 16 + o];
        else if (o < 32)  v = w1[2048 + i * 16 + (o - 16)];
        else              v = root1[i * 16 + (o - 32)];
        W[o * 132 + i] = v;
    }
    __syncthreads();

    int nl = threadIdx.x >> 4;
    int o  = threadIdx.x & 15;
    int n  = blockIdx.x * 16 + nl;      // 3125*16 = 50000 exact

    const float4* xr = (const float4*)(x + (size_t)n * N_FEAT);
    float a0 = 0.f, a1 = 0.f, ar = 0.f;
#pragma unroll
    for (int i4 = 0; i4 < 32; ++i4) {
        float4 xv = xr[i4];
        float4 wa = *(const float4*)&W[o * 132 + 4 * i4];
        float4 wb = *(const float4*)&W[(o + 16) * 132 + 4 * i4];
        float4 wr = *(const float4*)&W[(o + 32) * 132 + 4 * i4];
        a0 += xv.x * wa.x + xv.y * wa.y + xv.z * wa.z + xv.w * wa.w;
        a1 += xv.x * wb.x + xv.y * wb.y + xv.z * wb.z + xv.w * wb.w;
        ar += xv.x * wr.x + xv.y * wr.y + xv.z * wr.z + xv.w * wr.w;
    }
    AB[(size_t)n * 32 + o]      = a0;
    AB[(size_t)n * 32 + 16 + o] = a1;
    C[(size_t)n * 16 + o]       = ar + b1[o];
}

// ---------------------------------------------------------------------------
// CSR build: histogram, 3-stage parallel scan, reorder (packed int2 payload).
// ---------------------------------------------------------------------------
__global__ __launch_bounds__(256) void k_hist(
    const int* __restrict__ dst, int* __restrict__ cnt)
{
    int e = blockIdx.x * 256 + threadIdx.x;   // 3125*256 = 800000 exact
    atomicAdd(&cnt[dst[e]], 1);
}

// Stage A: per-block (256 counters) local exclusive prefix + block total.
__global__ __launch_bounds__(256) void k_scanA(
    const int* __restrict__ cnt, int* __restrict__ locpre,
    int* __restrict__ blksum)
{
    __shared__ int s[256];
    int t = threadIdx.x;
    int n = blockIdx.x * 256 + t;
    int v = (n < N_NODES) ? cnt[n] : 0;
    s[t] = v;
    __syncthreads();
#pragma unroll
    for (int off = 1; off < 256; off <<= 1) {
        int w = (t >= off) ? s[t - off] : 0;
        __syncthreads();
        s[t] += w;
        __syncthreads();
    }
    if (n < N_NODES) locpre[n] = s[t] - v;
    if (t == 255) blksum[blockIdx.x] = s[255];
}

// Stage B: single block scans the SCAN_NB block totals -> exclusive offsets.
__global__ __launch_bounds__(256) void k_scanB(
    const int* __restrict__ blksum, int* __restrict__ blkoff)
{
    __shared__ int s[256];
    int t = threadIdx.x;
    int v = (t < SCAN_NB) ? blksum[t] : 0;
    s[t] = v;
    __syncthreads();
#pragma unroll
    for (int off = 1; off < 256; off <<= 1) {
        int w = (t >= off) ? s[t - off] : 0;
        __syncthreads();
        s[t] += w;
        __syncthreads();
    }
    if (t < SCAN_NB) blkoff[t] = s[t] - v;
}

// Stage C: rowptr/cursor = locpre + blkoff.
__global__ __launch_bounds__(256) void k_scanC(
    const int* __restrict__ locpre, const int* __restrict__ blkoff,
    int* __restrict__ rowptr, int* __restrict__ cursor)
{
    int n = blockIdx.x * 256 + threadIdx.x;
    if (n < N_NODES) {
        int r = locpre[n] + blkoff[blockIdx.x];
        rowptr[n] = r;
        cursor[n] = r;
    }
    if (n == 0) rowptr[N_NODES] = N_EDGES;
}

__global__ __launch_bounds__(256) void k_reorder(
    const int* __restrict__ src, const int* __restrict__ dst,
    const float* __restrict__ u, int* __restrict__ cursor,
    int2* __restrict__ ep)
{
    int e = blockIdx.x * 256 + threadIdx.x;   // exact
    int d = dst[e];
    int pos = atomicAdd(&cursor[d], 1);
    ep[pos] = make_int2(src[e], __float_as_int(u[e]));
}

// ---------------------------------------------------------------------------
// Gather-mean: one wave per dst node; 4 edge slots x 16 features per lane.
// ---------------------------------------------------------------------------
__global__ __launch_bounds__(256) void k_gather(
    const int* __restrict__ rowptr, const int2* __restrict__ ep,
    const float* __restrict__ AB, float* __restrict__ AGG)
{
    int n    = (blockIdx.x * 256 + threadIdx.x) >> 6;  // 12500*4 = 50000
    int lane = threadIdx.x & 63;
    int o = lane & 15;
    int g = lane >> 4;
    int beg = rowptr[n], end = rowptr[n + 1];
    float acc = 0.f;
    for (int e = beg + g; e < end; e += 4) {
        int2 p = ep[e];
        float uv = __int_as_float(p.y);
        acc += (1.f - uv) * AB[(size_t)p.x * 32 + o]
             +        uv  * AB[(size_t)p.x * 32 + 16 + o];
    }
    acc += __shfl_xor(acc, 16);
    acc += __shfl_xor(acc, 32);
    float dv = fmaxf((float)(end - beg), 1.f);
    if (lane < 16) AGG[(size_t)n * 16 + o] = acc / dv;
}

// ---------------------------------------------------------------------------
// K3: finish layer 1 (agg already meaned) + ELU + layer-2 node transform.
// ---------------------------------------------------------------------------
__global__ __launch_bounds__(256) void k_node2(
    const float* __restrict__ agg, float* __restrict__ C,
    const float* __restrict__ w2, const float* __restrict__ root2,
    const float* __restrict__ b2, float* __restrict__ AB)
{
    __shared__ float W2[16 * 48];
    __shared__ float hl[16][17];
    for (int t = threadIdx.x; t < 16 * 48; t += 256) {
        int j = t / 48, o = t % 48;
        float v;
        if (o < 16)       v = w2[j * 16 + o];
        else if (o < 32)  v = w2[256 + j * 16 + (o - 16)];
        else              v = root2[j * 16 + (o - 32)];
        W2[t] = v;
    }
    int nl = threadIdx.x >> 4;
    int o  = threadIdx.x & 15;
    int n  = blockIdx.x * 16 + nl;

    float pre = agg[(size_t)n * 16 + o] + C[(size_t)n * 16 + o];
    float h   = pre > 0.f ? pre : expm1f(pre);
    __syncthreads();
    hl[nl][o] = h;
    __syncthreads();

    float a = 0.f, b = 0.f, p = 0.f;
#pragma unroll
    for (int j = 0; j < 16; ++j) {
        float hv = hl[nl][j];
        a += hv * W2[j * 48 + o];
        b += hv * W2[j * 48 + 16 + o];
        p += hv * W2[j * 48 + 32 + o];
    }
    AB[(size_t)n * 32 + o]      = a;
    AB[(size_t)n * 32 + 16 + o] = b;
    C[(size_t)n * 16 + o]       = p + b2[o];
}

// ---------------------------------------------------------------------------
// K5: log_softmax over 16 classes.
// ---------------------------------------------------------------------------
__global__ __launch_bounds__(256) void k_final(
    const float* __restrict__ agg, const float* __restrict__ C,
    float* __restrict__ out)
{
    int t = blockIdx.x * 256 + threadIdx.x;
    int n = t >> 4;
    int o = t & 15;
    float v = agg[(size_t)n * 16 + o] + C[(size_t)n * 16 + o];
    float m = v;
#pragma unroll
    for (int s = 1; s < 16; s <<= 1) m = fmaxf(m, __shfl_xor(m, s, 16));
    float ex = __expf(v - m);
    float ssum = ex;
#pragma unroll
    for (int s = 1; s < 16; s <<= 1) ssum += __shfl_xor(ssum, s, 16);
    out[(size_t)n * 16 + o] = v - m - __logf(ssum);
}

extern "C" void kernel_launch(void* const* d_in, const int* in_sizes, int n_in,
                              void* d_out, int out_size, void* d_ws, size_t ws_size,
                              hipStream_t stream) {
    const float* x     = (const float*)d_in[0];
    const int*   ei    = (const int*)d_in[1];
    const float* ea    = (const float*)d_in[2];
    const float* w1    = (const float*)d_in[3];
    const float* root1 = (const float*)d_in[4];
    const float* b1    = (const float*)d_in[5];
    const float* w2    = (const float*)d_in[6];
    const float* root2 = (const float*)d_in[7];
    const float* b2    = (const float*)d_in[8];
    float* out = (float*)d_out;

    char* ws = (char*)d_ws;
    float* AB     = (float*)ws;                                   // N*32
    float* C      = AB + (size_t)N_NODES * 32;                    // N*16
    float* AGG    = C + (size_t)N_NODES * 16;                     // N*16
    int2*  EP     = (int2*)(AGG + (size_t)N_NODES * 16);          // E int2
    int*   CNT    = (int*)(EP + N_EDGES);                         // N
    int*   LOCPRE = CNT + N_NODES;                                // N
    int*   ROWPTR = LOCPRE + N_NODES;                             // N+1
    int*   CURSOR = ROWPTR + (N_NODES + 1);                       // N
    int*   BLKSUM = CURSOR + N_NODES;                             // SCAN_NB
    int*   BLKOFF = BLKSUM + SCAN_NB;                             // SCAN_NB

    const int* srcp = ei;
    const int* dstp = ei + N_EDGES;

    hipMemsetAsync(CNT, 0, (size_t)N_NODES * sizeof(int), stream);

    k_node1<<<N_NODES / 16, 256, 0, stream>>>(x, w1, root1, b1, AB, C);
    k_hist<<<N_EDGES / 256, 256, 0, stream>>>(dstp, CNT);
    k_scanA<<<SCAN_NB, 256, 0, stream>>>(CNT, LOCPRE, BLKSUM);
    k_scanB<<<1, 256, 0, stream>>>(BLKSUM, BLKOFF);
    k_scanC<<<SCAN_NB, 256, 0, stream>>>(LOCPRE, BLKOFF, ROWPTR, CURSOR);
    k_reorder<<<N_EDGES / 256, 256, 0, stream>>>(srcp, dstp, ea, CURSOR, EP);

    k_gather<<<N_NODES / 4, 256, 0, stream>>>(ROWPTR, EP, AB, AGG);
    k_node2<<<N_NODES / 16, 256, 0, stream>>>(AGG, C, w2, root2, b2, AB);
    k_gather<<<N_NODES / 4, 256, 0, stream>>>(ROWPTR, EP, AB, AGG);
    k_final<<<N_NODES / 16, 256, 0, stream>>>(AGG, C, out);
}

// Round 4
// 208.562 us; speedup vs baseline: 1.5421x; 1.0762x over previous
//
#include <hip/hip_runtime.h>
#include <hip/hip_bf16.h>
#include <math.h>

#define N_NODES 50000
#define N_EDGES 800000
#define N_FEAT 128
#define HIDDEN 16
#define N_CLASSES 16

#define SCAN_NB 196   // ceil(50000/256)

// ---------------------------------------------------------------------------
// K1: per-node transform for layer 1.
// h0 = x@w1[0], h1 = x@w1[1], p1 = x@root1 + b1.
// AB[N][32]: cols 0..15 = h0, 16..31 = h1 (one 128B row per node).
// Thread (g = tid>>4, o = tid&15) computes 4 nodes x 3 outputs -> W LDS
// reads amortized 4x vs one-node-per-thread (R3 was LDS-pipe-bound).
// x loads are 16-lane-uniform broadcasts (4 distinct float4 per group).
// ---------------------------------------------------------------------------
__global__ __launch_bounds__(256) void k_node1(
    const float* __restrict__ x, const float* __restrict__ w1,
    const float* __restrict__ root1, const float* __restrict__ b1,
    float* __restrict__ AB, float* __restrict__ C)
{
    __shared__ float W[48 * 132];
    for (int t = threadIdx.x; t < 48 * 128; t += 256) {
        int o = t >> 7;
        int i = t & 127;
        float v;
        if (o < 16)       v = w1[i * 16 + o];
        else if (o < 32)  v = w1[2048 + i * 16 + (o - 16)];
        else              v = root1[i * 16 + (o - 32)];
        W[o * 132 + i] = v;
    }
    __syncthreads();

    int o = threadIdx.x & 15;
    int g = threadIdx.x >> 4;
    int nbase = blockIdx.x * 64 + g * 4;   // grid 782: covers 50048, guard stores

    int n0 = min(nbase + 0, N_NODES - 1);
    int n1 = min(nbase + 1, N_NODES - 1);
    int n2 = min(nbase + 2, N_NODES - 1);
    int n3 = min(nbase + 3, N_NODES - 1);

    const float4* x0 = (const float4*)(x + (size_t)n0 * N_FEAT);
    const float4* x1 = (const float4*)(x + (size_t)n1 * N_FEAT);
    const float4* x2 = (const float4*)(x + (size_t)n2 * N_FEAT);
    const float4* x3 = (const float4*)(x + (size_t)n3 * N_FEAT);

    float acc[4][3];
#pragma unroll
    for (int j = 0; j < 4; ++j)
#pragma unroll
        for (int k = 0; k < 3; ++k) acc[j][k] = 0.f;

#pragma unroll 4
    for (int i4 = 0; i4 < 32; ++i4) {
        float4 wa = *(const float4*)&W[o * 132 + 4 * i4];
        float4 wb = *(const float4*)&W[(o + 16) * 132 + 4 * i4];
        float4 wr = *(const float4*)&W[(o + 32) * 132 + 4 * i4];
        float4 xv[4];
        xv[0] = x0[i4]; xv[1] = x1[i4]; xv[2] = x2[i4]; xv[3] = x3[i4];
#pragma unroll
        for (int j = 0; j < 4; ++j) {
            acc[j][0] += xv[j].x * wa.x + xv[j].y * wa.y + xv[j].z * wa.z + xv[j].w * wa.w;
            acc[j][1] += xv[j].x * wb.x + xv[j].y * wb.y + xv[j].z * wb.z + xv[j].w * wb.w;
            acc[j][2] += xv[j].x * wr.x + xv[j].y * wr.y + xv[j].z * wr.z + xv[j].w * wr.w;
        }
    }

    float bo = b1[o];
#pragma unroll
    for (int j = 0; j < 4; ++j) {
        int n = nbase + j;
        if (n < N_NODES) {
            AB[(size_t)n * 32 + o]      = acc[j][0];
            AB[(size_t)n * 32 + 16 + o] = acc[j][1];
            C[(size_t)n * 16 + o]       = acc[j][2] + bo;
        }
    }
}

// ---------------------------------------------------------------------------
// CSR build: histogram, 3-stage parallel scan, reorder (packed int2 payload).
// ---------------------------------------------------------------------------
__global__ __launch_bounds__(256) void k_hist(
    const int* __restrict__ dst, int* __restrict__ cnt)
{
    int e = blockIdx.x * 256 + threadIdx.x;   // 3125*256 = 800000 exact
    atomicAdd(&cnt[dst[e]], 1);
}

// Stage A: per-block (256 counters) local exclusive prefix + block total.
__global__ __launch_bounds__(256) void k_scanA(
    const int* __restrict__ cnt, int* __restrict__ locpre,
    int* __restrict__ blksum)
{
    __shared__ int s[256];
    int t = threadIdx.x;
    int n = blockIdx.x * 256 + t;
    int v = (n < N_NODES) ? cnt[n] : 0;
    s[t] = v;
    __syncthreads();
#pragma unroll
    for (int off = 1; off < 256; off <<= 1) {
        int w = (t >= off) ? s[t - off] : 0;
        __syncthreads();
        s[t] += w;
        __syncthreads();
    }
    if (n < N_NODES) locpre[n] = s[t] - v;
    if (t == 255) blksum[blockIdx.x] = s[255];
}

// Stage B: single block scans the SCAN_NB block totals -> exclusive offsets.
__global__ __launch_bounds__(256) void k_scanB(
    const int* __restrict__ blksum, int* __restrict__ blkoff)
{
    __shared__ int s[256];
    int t = threadIdx.x;
    int v = (t < SCAN_NB) ? blksum[t] : 0;
    s[t] = v;
    __syncthreads();
#pragma unroll
    for (int off = 1; off < 256; off <<= 1) {
        int w = (t >= off) ? s[t - off] : 0;
        __syncthreads();
        s[t] += w;
        __syncthreads();
    }
    if (t < SCAN_NB) blkoff[t] = s[t] - v;
}

// Stage C: rowptr/cursor = locpre + blkoff.
__global__ __launch_bounds__(256) void k_scanC(
    const int* __restrict__ locpre, const int* __restrict__ blkoff,
    int* __restrict__ rowptr, int* __restrict__ cursor)
{
    int n = blockIdx.x * 256 + threadIdx.x;
    if (n < N_NODES) {
        int r = locpre[n] + blkoff[blockIdx.x];
        rowptr[n] = r;
        cursor[n] = r;
    }
    if (n == 0) rowptr[N_NODES] = N_EDGES;
}

__global__ __launch_bounds__(256) void k_reorder(
    const int* __restrict__ src, const int* __restrict__ dst,
    const float* __restrict__ u, int* __restrict__ cursor,
    int2* __restrict__ ep)
{
    int e = blockIdx.x * 256 + threadIdx.x;   // exact
    int d = dst[e];
    int pos = atomicAdd(&cursor[d], 1);
    ep[pos] = make_int2(src[e], __float_as_int(u[e]));
}

// ---------------------------------------------------------------------------
// Gather-mean: one wave per dst node; 4 edge slots x 16 features per lane.
// ---------------------------------------------------------------------------
__global__ __launch_bounds__(256) void k_gather(
    const int* __restrict__ rowptr, const int2* __restrict__ ep,
    const float* __restrict__ AB, float* __restrict__ AGG)
{
    int n    = (blockIdx.x * 256 + threadIdx.x) >> 6;  // 12500*4 = 50000
    int lane = threadIdx.x & 63;
    int o = lane & 15;
    int g = lane >> 4;
    int beg = rowptr[n], end = rowptr[n + 1];
    float acc = 0.f;
    for (int e = beg + g; e < end; e += 4) {
        int2 p = ep[e];
        float uv = __int_as_float(p.y);
        acc += (1.f - uv) * AB[(size_t)p.x * 32 + o]
             +        uv  * AB[(size_t)p.x * 32 + 16 + o];
    }
    acc += __shfl_xor(acc, 16);
    acc += __shfl_xor(acc, 32);
    float dv = fmaxf((float)(end - beg), 1.f);
    if (lane < 16) AGG[(size_t)n * 16 + o] = acc / dv;
}

// ---------------------------------------------------------------------------
// K3: finish layer 1 (agg already meaned) + ELU + layer-2 node transform.
// ---------------------------------------------------------------------------
__global__ __launch_bounds__(256) void k_node2(
    const float* __restrict__ agg, float* __restrict__ C,
    const float* __restrict__ w2, const float* __restrict__ root2,
    const float* __restrict__ b2, float* __restrict__ AB)
{
    __shared__ float W2[16 * 48];
    __shared__ float hl[16][17];
    for (int t = threadIdx.x; t < 16 * 48; t += 256) {
        int j = t / 48, o = t % 48;
        float v;
        if (o < 16)       v = w2[j * 16 + o];
        else if (o < 32)  v = w2[256 + j * 16 + (o - 16)];
        else              v = root2[j * 16 + (o - 32)];
        W2[t] = v;
    }
    int nl = threadIdx.x >> 4;
    int o  = threadIdx.x & 15;
    int n  = blockIdx.x * 16 + nl;

    float pre = agg[(size_t)n * 16 + o] + C[(size_t)n * 16 + o];
    float h   = pre > 0.f ? pre : expm1f(pre);
    __syncthreads();
    hl[nl][o] = h;
    __syncthreads();

    float a = 0.f, b = 0.f, p = 0.f;
#pragma unroll
    for (int j = 0; j < 16; ++j) {
        float hv = hl[nl][j];
        a += hv * W2[j * 48 + o];
        b += hv * W2[j * 48 + 16 + o];
        p += hv * W2[j * 48 + 32 + o];
    }
    AB[(size_t)n * 32 + o]      = a;
    AB[(size_t)n * 32 + 16 + o] = b;
    C[(size_t)n * 16 + o]       = p + b2[o];
}

// ---------------------------------------------------------------------------
// K5: log_softmax over 16 classes.
// ---------------------------------------------------------------------------
__global__ __launch_bounds__(256) void k_final(
    const float* __restrict__ agg, const float* __restrict__ C,
    float* __restrict__ out)
{
    int t = blockIdx.x * 256 + threadIdx.x;
    int n = t >> 4;
    int o = t & 15;
    float v = agg[(size_t)n * 16 + o] + C[(size_t)n * 16 + o];
    float m = v;
#pragma unroll
    for (int s = 1; s < 16; s <<= 1) m = fmaxf(m, __shfl_xor(m, s, 16));
    float ex = __expf(v - m);
    float ssum = ex;
#pragma unroll
    for (int s = 1; s < 16; s <<= 1) ssum += __shfl_xor(ssum, s, 16);
    out[(size_t)n * 16 + o] = v - m - __logf(ssum);
}

extern "C" void kernel_launch(void* const* d_in, const int* in_sizes, int n_in,
                              void* d_out, int out_size, void* d_ws, size_t ws_size,
                              hipStream_t stream) {
    const float* x     = (const float*)d_in[0];
    const int*   ei    = (const int*)d_in[1];
    const float* ea    = (const float*)d_in[2];
    const float* w1    = (const float*)d_in[3];
    const float* root1 = (const float*)d_in[4];
    const float* b1    = (const float*)d_in[5];
    const float* w2    = (const float*)d_in[6];
    const float* root2 = (const float*)d_in[7];
    const float* b2    = (const float*)d_in[8];
    float* out = (float*)d_out;

    char* ws = (char*)d_ws;
    float* AB     = (float*)ws;                                   // N*32
    float* C      = AB + (size_t)N_NODES * 32;                    // N*16
    float* AGG    = C + (size_t)N_NODES * 16;                     // N*16
    int2*  EP     = (int2*)(AGG + (size_t)N_NODES * 16);          // E int2
    int*   CNT    = (int*)(EP + N_EDGES);                         // N
    int*   LOCPRE = CNT + N_NODES;                                // N
    int*   ROWPTR = LOCPRE + N_NODES;                             // N+1
    int*   CURSOR = ROWPTR + (N_NODES + 1);                       // N
    int*   BLKSUM = CURSOR + N_NODES;                             // SCAN_NB
    int*   BLKOFF = BLKSUM + SCAN_NB;                             // SCAN_NB

    const int* srcp = ei;
    const int* dstp = ei + N_EDGES;

    hipMemsetAsync(CNT, 0, (size_t)N_NODES * sizeof(int), stream);

    k_node1<<<782, 256, 0, stream>>>(x, w1, root1, b1, AB, C);
    k_hist<<<N_EDGES / 256, 256, 0, stream>>>(dstp, CNT);
    k_scanA<<<SCAN_NB, 256, 0, stream>>>(CNT, LOCPRE, BLKSUM);
    k_scanB<<<1, 256, 0, stream>>>(BLKSUM, BLKOFF);
    k_scanC<<<SCAN_NB, 256, 0, stream>>>(LOCPRE, BLKOFF, ROWPTR, CURSOR);
    k_reorder<<<N_EDGES / 256, 256, 0, stream>>>(srcp, dstp, ea, CURSOR, EP);

    k_gather<<<N_NODES / 4, 256, 0, stream>>>(ROWPTR, EP, AB, AGG);
    k_node2<<<N_NODES / 16, 256, 0, stream>>>(AGG, C, w2, root2, b2, AB);
    k_gather<<<N_NODES / 4, 256, 0, stream>>>(ROWPTR, EP, AB, AGG);
    k_final<<<N_NODES / 16, 256, 0, stream>>>(AGG, C, out);
}